// Round 17
// baseline (127.410 us; speedup 1.0000x reference)
//
#include <hip/hip_runtime.h>
#include <math.h>

#define BB 64
#define LL 256
#define DD 1024
#define NDPAD 512   // padded anti-diagonal count per batch (511 real + 1 pad)
#define BK 32
#define LOG2E 1.4426950408889634f
#define LN2   0.6931471805599453f

typedef __attribute__((ext_vector_type(8))) short short8v;
typedef __attribute__((ext_vector_type(4))) float float4v;

__device__ __forceinline__ unsigned short f2bf(float f) {
    unsigned u = __float_as_uint(f);
    unsigned r = (u + 0x7fffu + ((u >> 16) & 1u)) >> 16;   // RNE
    return (unsigned short)r;
}
__device__ __forceinline__ float bf2f(unsigned short u) {
    return __uint_as_float(((unsigned)u) << 16);
}
// packed RNE convert: dst = (bf16(hi)<<16) | bf16(lo)
__device__ __forceinline__ unsigned cvtpk(float lo, float hi) {
    unsigned r;
    asm("v_cvt_pk_bf16_f32 %0, %1, %2" : "=v"(r) : "v"(lo), "v"(hi));
    return r;
}

// ================= REAL PIPELINE (identical to round 16) =================
__global__ __launch_bounds__(512) void fused_kernel(const float* __restrict__ S,
                                                    const float* __restrict__ T,
                                                    unsigned short* __restrict__ Dd) {
    __shared__ unsigned short lds[2][2][2][128 * BK];   // [pipe][buf][A/B], 64 KB
    __shared__ float nrmP[2][2][128];                   // partial norms [pipe][side][row]

    const int b    = blockIdx.x;
    const int tile = blockIdx.y;
    const int i0 = (tile & 1) * 128;
    const int j0 = (tile >> 1) * 128;
    const int tid = threadIdx.x, w = tid >> 6, lane = tid & 63;
    const int p = w >> 2;
    const int q = w & 3;
    const int wr = q >> 1, wc = q & 1;
    const int kbase = p * 512;

    const float* Sg = S + ((size_t)b * LL + i0) * DD;
    const float* Tg = T + ((size_t)b * LL + j0) * DD;

    const int sr   = q * 16 + (lane >> 2);
    const int slot = lane & 3;
    const int kb   = slot ^ ((sr >> 1) & 3);

    float4v acc[4][4];
    const float4v fzero = {0.f, 0.f, 0.f, 0.f};
    #pragma unroll
    for (int mi = 0; mi < 4; ++mi)
        #pragma unroll
        for (int ni = 0; ni < 4; ++ni) acc[mi][ni] = fzero;

    struct Stg { float4 a[2][2]; float4 bb[2][2]; };
    Stg st0, st1;
    float ns[2][2] = {};

    auto issue = [&](Stg& s, int kt) {
        const float* pa = Sg + (size_t)sr * DD + kbase + kt * BK + kb * 8;
        const float* pb = Tg + (size_t)sr * DD + kbase + kt * BK + kb * 8;
        s.a[0][0]  = *(const float4*)(pa);
        s.a[0][1]  = *(const float4*)(pa + 4);
        s.a[1][0]  = *(const float4*)(pa + 64 * DD);
        s.a[1][1]  = *(const float4*)(pa + 64 * DD + 4);
        s.bb[0][0] = *(const float4*)(pb);
        s.bb[0][1] = *(const float4*)(pb + 4);
        s.bb[1][0] = *(const float4*)(pb + 64 * DD);
        s.bb[1][1] = *(const float4*)(pb + 64 * DD + 4);
    };

    auto cvtwrite = [&](const float4& v0, const float4& v1, unsigned short* dst, float& nacc) {
        nacc += v0.x * v0.x + v0.y * v0.y + v0.z * v0.z + v0.w * v0.w
              + v1.x * v1.x + v1.y * v1.y + v1.z * v1.z + v1.w * v1.w;
        uint4 o;
        o.x = cvtpk(v0.x, v0.y);
        o.y = cvtpk(v0.z, v0.w);
        o.z = cvtpk(v1.x, v1.y);
        o.w = cvtpk(v1.z, v1.w);
        *(uint4*)dst = o;
    };

    auto commit = [&](Stg& s, int buf) {
        #pragma unroll
        for (int n = 0; n < 2; ++n) {
            cvtwrite(s.a[n][0],  s.a[n][1],  &lds[p][buf][0][(n * 64 + sr) * BK + slot * 8], ns[0][n]);
            cvtwrite(s.bb[n][0], s.bb[n][1], &lds[p][buf][1][(n * 64 + sr) * BK + slot * 8], ns[1][n]);
        }
    };

    auto compute = [&](int buf) {
        const unsigned short* LA = &lds[p][buf][0][0];
        const unsigned short* LB = &lds[p][buf][1][0];
        short8v af[4], bf[4];
        #pragma unroll
        for (int mi = 0; mi < 4; ++mi) {
            int row = wr * 64 + mi * 16 + (lane & 15);
            int kbf = (lane >> 4) ^ ((row >> 1) & 3);
            af[mi] = *(const short8v*)(LA + row * BK + kbf * 8);
        }
        #pragma unroll
        for (int ni = 0; ni < 4; ++ni) {
            int row = wc * 64 + ni * 16 + (lane & 15);
            int kbf = (lane >> 4) ^ ((row >> 1) & 3);
            bf[ni] = *(const short8v*)(LB + row * BK + kbf * 8);
        }
        #pragma unroll
        for (int mi = 0; mi < 4; ++mi)
            #pragma unroll
            for (int ni = 0; ni < 4; ++ni)
                acc[mi][ni] = __builtin_amdgcn_mfma_f32_16x16x32_bf16(af[mi], bf[ni],
                                                                      acc[mi][ni], 0, 0, 0);
    };

    auto phase_barrier = [&]() {
        asm volatile("s_waitcnt lgkmcnt(0)" ::: "memory");
        __builtin_amdgcn_s_barrier();
        __builtin_amdgcn_sched_barrier(0);
    };

    issue(st0, 0);
    for (int kt2 = 0; kt2 < 16; kt2 += 2) {
        issue(st1, kt2 + 1);
        commit(st0, 0);
        phase_barrier();
        compute(0);
        if (kt2 + 2 < 16) issue(st0, kt2 + 2);
        commit(st1, 1);
        phase_barrier();
        compute(1);
    }

    #pragma unroll
    for (int side = 0; side < 2; ++side)
        #pragma unroll
        for (int n = 0; n < 2; ++n) {
            float s = ns[side][n];
            s += __shfl_xor(s, 1, 64);
            s += __shfl_xor(s, 2, 64);
            if (slot == 0) nrmP[p][side][n * 64 + sr] = s;
        }
    __syncthreads();

    float* cb = (float*)&lds[0][0][0][0];
    if (p == 1) {
        #pragma unroll
        for (int mi = 0; mi < 4; ++mi)
            #pragma unroll
            for (int ni = 0; ni < 4; ++ni)
                *(float4v*)(cb + q * 4096 + (mi * 4 + ni) * 256 + lane * 4) = acc[mi][ni];
    }
    __syncthreads();

    if (p == 0) {
        #pragma unroll
        for (int mi = 0; mi < 4; ++mi)
            #pragma unroll
            for (int ni = 0; ni < 4; ++ni)
                acc[mi][ni] += *(const float4v*)(cb + q * 4096 + (mi * 4 + ni) * 256 + lane * 4);

        const int r0 = (lane >> 4) * 4;
        const int cf = lane & 15;
        unsigned short* Db = Dd + (size_t)b * NDPAD * 256;
        #pragma unroll
        for (int mi = 0; mi < 4; ++mi) {
            #pragma unroll
            for (int ni = 0; ni < 4; ++ni) {
                int lj = wc * 64 + ni * 16 + cf;
                float tj = nrmP[0][1][lj] + nrmP[1][1][lj];
                int j = j0 + lj;
                #pragma unroll
                for (int rg = 0; rg < 4; ++rg) {
                    int li = wr * 64 + mi * 16 + r0 + rg;
                    float sq = nrmP[0][0][li] + nrmP[1][0][li] + tj - 2.0f * acc[mi][ni][rg];
                    float dv = sqrtf(fmaxf(sq, 1e-12f));
                    int i = i0 + li;
                    Db[(size_t)(i + j) * 256 + j] = f2bf(dv * LOG2E);
                }
            }
        }
    }
}

// lane i <- lane i-1 via DPP wave_shr:1; lane 0 <- fill
__device__ __forceinline__ float wshr1(float src, float fill) {
    return __int_as_float(__builtin_amdgcn_update_dpp(
        __float_as_int(fill), __float_as_int(src), 0x138, 0xF, 0xF, false));
}

__global__ __launch_bounds__(256) void sdtw_kernel(const unsigned short* __restrict__ Dg,
                                                   float* __restrict__ res) {
    __shared__ unsigned short sd[8][16 * 256];
    __shared__ float bbuf[3][2][16];
    const int b = blockIdx.x;
    const int tid = threadIdx.x;
    const int w = tid >> 6;
    const int lane = tid & 63;
    const float INF = INFINITY;
    const unsigned short* Db = Dg + (size_t)b * NDPAD * 256;

    auto prefetch = [&](int c) {
        #pragma unroll
        for (int q = 0; q < 8; ++q) {
            __builtin_amdgcn_global_load_lds(
                (const __attribute__((address_space(1))) void*)(Db + (size_t)c * 4096 + q * 512 + lane * 8),
                (__attribute__((address_space(3))) void*)(&sd[c & 7][q * 512]),
                16, 0, 0);
        }
    };

    const int col0 = 64 * w + lane;
    float rm1 = INF, rm2 = INF;
    float p2carry = (tid == 0) ? 0.0f : INF;
    float bcarry = INF;

    if (w == 0) {
        prefetch(0);
        prefetch(1);
        asm volatile("s_waitcnt vmcnt(8)" ::: "memory");
    }
    asm volatile("s_waitcnt lgkmcnt(0)" ::: "memory");
    __builtin_amdgcn_s_barrier();

    for (int r = 0; r < 35; ++r) {
        if (w == 0 && r + 2 < 32) prefetch(r + 2);
        const int c = r - w;
        if (0 <= c && c < 32) {
            const unsigned short* Lp = &sd[c & 7][0];
            float dv[16];
            #pragma unroll
            for (int q = 0; q < 16; ++q)
                dv[q] = bf2f(Lp[q * 256 + col0]);

            float bv[16];
            if (w == 0) {
                #pragma unroll
                for (int q = 0; q < 16; ++q) bv[q] = INF;
            } else {
                const float4* bp4 = (const float4*)&bbuf[w - 1][c & 1][0];
                float4 b0 = bp4[0], b1 = bp4[1], b2 = bp4[2], b3 = bp4[3];
                bv[0] = bcarry;
                bv[1] = b0.x;  bv[2] = b0.y;  bv[3] = b0.z;  bv[4] = b0.w;
                bv[5] = b1.x;  bv[6] = b1.y;  bv[7] = b1.z;  bv[8] = b1.w;
                bv[9] = b2.x;  bv[10] = b2.y; bv[11] = b2.z; bv[12] = b2.w;
                bv[13] = b3.x; bv[14] = b3.y; bv[15] = b3.z;
                bcarry = b3.w;
            }
            asm volatile("s_waitcnt lgkmcnt(0)" ::: "memory");
            __builtin_amdgcn_sched_barrier(0);

            const int ibase = 16 * c - col0;
            float bb[16];
            #pragma unroll
            for (int q = 0; q < 16; ++q) {
                float p1 = wshr1(rm1, bv[q]);
                float p2 = p2carry;
                p2carry = p1;
                float m   = fminf(p2, fminf(rm1, p1));
                float mid = __builtin_amdgcn_fmed3f(p2, rm1, p1);
                float M   = fmaxf(p2, fmaxf(rm1, p1));
                float s   = (__builtin_amdgcn_exp2f(m - mid) +
                             __builtin_amdgcn_exp2f(m - M)) + 1.0f;
                float rcv = dv[q] + m - __builtin_amdgcn_logf(s);
                bool valid = (unsigned)(ibase + q) < 256u;
                rcv = valid ? rcv : INF;
                rm2 = rm1;
                rm1 = rcv;
                bb[q] = rcv;
            }
            if (w < 3 && lane == 63) {
                float4* op = (float4*)&bbuf[w][c & 1][0];
                op[0] = make_float4(bb[0], bb[1], bb[2], bb[3]);
                op[1] = make_float4(bb[4], bb[5], bb[6], bb[7]);
                op[2] = make_float4(bb[8], bb[9], bb[10], bb[11]);
                op[3] = make_float4(bb[12], bb[13], bb[14], bb[15]);
            }
        }
        if (w == 0) {
            if (r < 30) asm volatile("s_waitcnt vmcnt(8)" ::: "memory");
            else        asm volatile("s_waitcnt vmcnt(0)" ::: "memory");
        }
        asm volatile("s_waitcnt lgkmcnt(0)" ::: "memory");
        __builtin_amdgcn_s_barrier();
    }
    if (tid == 255) res[b] = rm2 * LN2;
}

__global__ void reduce_kernel(const float* __restrict__ res, float* __restrict__ out) {
    int t = threadIdx.x;
    float v = res[t];
    #pragma unroll
    for (int off = 32; off; off >>= 1) v += __shfl_down(v, off, 64);
    if (t == 0) out[0] = v * (1.0f / BB);
}

// ================= DIAGNOSTIC ABLATIONS (run AFTER the real pipeline) =================
// Each reproduces one slice of fused's per-half-phase structure at identical
// geometry. Results written to dummy to defeat DCE (rule #17).

// A) barrier/loop skeleton only
__global__ __launch_bounds__(512) void abl_sync(float* __restrict__ dummy) {
    float x = (float)threadIdx.x;
    for (int h = 0; h < 16; ++h) {
        x = x * 1.000001f + 1.0f;
        asm volatile("s_waitcnt lgkmcnt(0)" ::: "memory");
        __builtin_amdgcn_s_barrier();
        __builtin_amdgcn_sched_barrier(0);
    }
    dummy[((size_t)blockIdx.y * 64 + blockIdx.x) * 512 + threadIdx.x] = x;
}

// B) VMEM path: identical issue/consume rotation, no LDS, no MFMA
__global__ __launch_bounds__(512) void abl_vmem(const float* __restrict__ S,
                                                const float* __restrict__ T,
                                                float* __restrict__ dummy) {
    const int b    = blockIdx.x;
    const int tile = blockIdx.y;
    const int i0 = (tile & 1) * 128;
    const int j0 = (tile >> 1) * 128;
    const int tid = threadIdx.x, w = tid >> 6, lane = tid & 63;
    const int p = w >> 2, q = w & 3;
    const int kbase = p * 512;
    const float* Sg = S + ((size_t)b * LL + i0) * DD;
    const float* Tg = T + ((size_t)b * LL + j0) * DD;
    const int sr   = q * 16 + (lane >> 2);
    const int slot = lane & 3;
    const int kb   = slot ^ ((sr >> 1) & 3);

    struct Stg { float4 a[2][2]; float4 bb[2][2]; };
    Stg st0, st1;
    float ns = 0.0f;

    auto issue = [&](Stg& s, int kt) {
        const float* pa = Sg + (size_t)sr * DD + kbase + kt * BK + kb * 8;
        const float* pb = Tg + (size_t)sr * DD + kbase + kt * BK + kb * 8;
        s.a[0][0]  = *(const float4*)(pa);
        s.a[0][1]  = *(const float4*)(pa + 4);
        s.a[1][0]  = *(const float4*)(pa + 64 * DD);
        s.a[1][1]  = *(const float4*)(pa + 64 * DD + 4);
        s.bb[0][0] = *(const float4*)(pb);
        s.bb[0][1] = *(const float4*)(pb + 4);
        s.bb[1][0] = *(const float4*)(pb + 64 * DD);
        s.bb[1][1] = *(const float4*)(pb + 64 * DD + 4);
    };
    auto consume = [&](Stg& s) {
        #pragma unroll
        for (int n = 0; n < 2; ++n) {
            ns += s.a[n][0].x * s.a[n][0].x + s.a[n][0].y * s.a[n][0].y
                + s.a[n][0].z * s.a[n][0].z + s.a[n][0].w * s.a[n][0].w;
            ns += s.a[n][1].x + s.a[n][1].y + s.a[n][1].z + s.a[n][1].w;
            ns += s.bb[n][0].x * s.bb[n][0].x + s.bb[n][0].y * s.bb[n][0].y
                + s.bb[n][0].z * s.bb[n][0].z + s.bb[n][0].w * s.bb[n][0].w;
            ns += s.bb[n][1].x + s.bb[n][1].y + s.bb[n][1].z + s.bb[n][1].w;
        }
    };
    auto pb_ = [&]() {
        asm volatile("s_waitcnt lgkmcnt(0)" ::: "memory");
        __builtin_amdgcn_s_barrier();
        __builtin_amdgcn_sched_barrier(0);
    };

    issue(st0, 0);
    for (int kt2 = 0; kt2 < 16; kt2 += 2) {
        issue(st1, kt2 + 1);
        consume(st0);
        pb_();
        if (kt2 + 2 < 16) issue(st0, kt2 + 2);
        consume(st1);
        pb_();
    }
    dummy[((size_t)blockIdx.y * 64 + blockIdx.x) * 512 + tid] = ns;
}

// C) VMEM + cvt + LDS-write path (full staging), no compute
__global__ __launch_bounds__(512) void abl_stage(const float* __restrict__ S,
                                                 const float* __restrict__ T,
                                                 float* __restrict__ dummy) {
    __shared__ unsigned short lds[2][2][2][128 * BK];
    const int b    = blockIdx.x;
    const int tile = blockIdx.y;
    const int i0 = (tile & 1) * 128;
    const int j0 = (tile >> 1) * 128;
    const int tid = threadIdx.x, w = tid >> 6, lane = tid & 63;
    const int p = w >> 2, q = w & 3;
    const int kbase = p * 512;
    const float* Sg = S + ((size_t)b * LL + i0) * DD;
    const float* Tg = T + ((size_t)b * LL + j0) * DD;
    const int sr   = q * 16 + (lane >> 2);
    const int slot = lane & 3;
    const int kb   = slot ^ ((sr >> 1) & 3);

    struct Stg { float4 a[2][2]; float4 bb[2][2]; };
    Stg st0, st1;
    float ns[2][2] = {};

    auto issue = [&](Stg& s, int kt) {
        const float* pa = Sg + (size_t)sr * DD + kbase + kt * BK + kb * 8;
        const float* pb = Tg + (size_t)sr * DD + kbase + kt * BK + kb * 8;
        s.a[0][0]  = *(const float4*)(pa);
        s.a[0][1]  = *(const float4*)(pa + 4);
        s.a[1][0]  = *(const float4*)(pa + 64 * DD);
        s.a[1][1]  = *(const float4*)(pa + 64 * DD + 4);
        s.bb[0][0] = *(const float4*)(pb);
        s.bb[0][1] = *(const float4*)(pb + 4);
        s.bb[1][0] = *(const float4*)(pb + 64 * DD);
        s.bb[1][1] = *(const float4*)(pb + 64 * DD + 4);
    };
    auto cvtwrite = [&](const float4& v0, const float4& v1, unsigned short* dst, float& nacc) {
        nacc += v0.x * v0.x + v0.y * v0.y + v0.z * v0.z + v0.w * v0.w
              + v1.x * v1.x + v1.y * v1.y + v1.z * v1.z + v1.w * v1.w;
        uint4 o;
        o.x = cvtpk(v0.x, v0.y);
        o.y = cvtpk(v0.z, v0.w);
        o.z = cvtpk(v1.x, v1.y);
        o.w = cvtpk(v1.z, v1.w);
        *(uint4*)dst = o;
    };
    auto commit = [&](Stg& s, int buf) {
        #pragma unroll
        for (int n = 0; n < 2; ++n) {
            cvtwrite(s.a[n][0],  s.a[n][1],  &lds[p][buf][0][(n * 64 + sr) * BK + slot * 8], ns[0][n]);
            cvtwrite(s.bb[n][0], s.bb[n][1], &lds[p][buf][1][(n * 64 + sr) * BK + slot * 8], ns[1][n]);
        }
    };
    auto pb_ = [&]() {
        asm volatile("s_waitcnt lgkmcnt(0)" ::: "memory");
        __builtin_amdgcn_s_barrier();
        __builtin_amdgcn_sched_barrier(0);
    };

    issue(st0, 0);
    for (int kt2 = 0; kt2 < 16; kt2 += 2) {
        issue(st1, kt2 + 1);
        commit(st0, 0);
        pb_();
        if (kt2 + 2 < 16) issue(st0, kt2 + 2);
        commit(st1, 1);
        pb_();
    }
    float tail = ns[0][0] + ns[0][1] + ns[1][0] + ns[1][1]
               + bf2f(lds[p][0][0][tid]) + bf2f(lds[p][1][1][tid]);
    dummy[((size_t)blockIdx.y * 64 + blockIdx.x) * 512 + tid] = tail;
}

// D) LDS-read + MFMA path: LDS pre-filled once, 16 half-phases of compute+barrier
__global__ __launch_bounds__(512) void abl_mfma(float* __restrict__ dummy) {
    __shared__ unsigned short lds[2][2][2][128 * BK];
    const int tid = threadIdx.x, w = tid >> 6, lane = tid & 63;
    const int p = w >> 2, q = w & 3;
    const int wr = q >> 1, wc = q & 1;

    unsigned short* lf = &lds[0][0][0][0];
    for (int idx = tid; idx < 2 * 2 * 2 * 128 * BK; idx += 512) lf[idx] = 0x3f80;
    __syncthreads();

    float4v acc[4][4];
    const float4v fzero = {0.f, 0.f, 0.f, 0.f};
    #pragma unroll
    for (int mi = 0; mi < 4; ++mi)
        #pragma unroll
        for (int ni = 0; ni < 4; ++ni) acc[mi][ni] = fzero;

    auto compute = [&](int buf) {
        const unsigned short* LA = &lds[p][buf][0][0];
        const unsigned short* LB = &lds[p][buf][1][0];
        short8v af[4], bf[4];
        #pragma unroll
        for (int mi = 0; mi < 4; ++mi) {
            int row = wr * 64 + mi * 16 + (lane & 15);
            int kbf = (lane >> 4) ^ ((row >> 1) & 3);
            af[mi] = *(const short8v*)(LA + row * BK + kbf * 8);
        }
        #pragma unroll
        for (int ni = 0; ni < 4; ++ni) {
            int row = wc * 64 + ni * 16 + (lane & 15);
            int kbf = (lane >> 4) ^ ((row >> 1) & 3);
            bf[ni] = *(const short8v*)(LB + row * BK + kbf * 8);
        }
        #pragma unroll
        for (int mi = 0; mi < 4; ++mi)
            #pragma unroll
            for (int ni = 0; ni < 4; ++ni)
                acc[mi][ni] = __builtin_amdgcn_mfma_f32_16x16x32_bf16(af[mi], bf[ni],
                                                                      acc[mi][ni], 0, 0, 0);
    };

    for (int h = 0; h < 16; ++h) {
        compute(h & 1);
        asm volatile("s_waitcnt lgkmcnt(0)" ::: "memory");
        __builtin_amdgcn_s_barrier();
        __builtin_amdgcn_sched_barrier(0);
    }

    float r = 0.0f;
    #pragma unroll
    for (int mi = 0; mi < 4; ++mi)
        #pragma unroll
        for (int ni = 0; ni < 4; ++ni)
            r += acc[mi][ni][0] + acc[mi][ni][1] + acc[mi][ni][2] + acc[mi][ni][3];
    dummy[((size_t)blockIdx.y * 64 + blockIdx.x) * 512 + tid] = r;
}

extern "C" void kernel_launch(void* const* d_in, const int* in_sizes, int n_in,
                              void* d_out, int out_size, void* d_ws, size_t ws_size,
                              hipStream_t stream) {
    const float* S = (const float*)d_in[0];
    const float* T = (const float*)d_in[1];

    const size_t nDiag = (size_t)BB * NDPAD * 256;   // 8,388,608 ushorts (16.8 MB)
    unsigned short* diag = (unsigned short*)d_ws;
    float* rsv = (float*)(diag + nDiag);
    float* dummy = rsv + 64;
    const size_t dumN = (size_t)256 * 512;           // floats per ablation kernel
    const size_t need = nDiag * 2 + 64 * 4 + dumN * 4 * 4;

    // real pipeline first (output correctness independent of ablations)
    fused_kernel<<<dim3(BB, 4), 512, 0, stream>>>(S, T, diag);
    sdtw_kernel<<<BB, 256, 0, stream>>>(diag, rsv);
    reduce_kernel<<<1, 64, 0, stream>>>(rsv, (float*)d_out);

    // diagnostics (skipped if ws too small)
    if (ws_size >= need) {
        abl_sync<<<dim3(BB, 4), 512, 0, stream>>>(dummy);
        abl_vmem<<<dim3(BB, 4), 512, 0, stream>>>(S, T, dummy + dumN);
        abl_stage<<<dim3(BB, 4), 512, 0, stream>>>(S, T, dummy + 2 * dumN);
        abl_mfma<<<dim3(BB, 4), 512, 0, stream>>>(dummy + 3 * dumN);
    }
}

// Round 18
// 78.062 us; speedup vs baseline: 1.6322x; 1.6322x over previous
//
#include <hip/hip_runtime.h>
#include <math.h>

#define BB 64
#define LL 256
#define DD 1024
#define NDPAD 512   // padded anti-diagonal count per batch (511 real + 1 pad)
#define BK 32
#define LOG2E 1.4426950408889634f
#define LN2   0.6931471805599453f

typedef __attribute__((ext_vector_type(8))) short short8v;
typedef __attribute__((ext_vector_type(4))) float float4v;

__device__ __forceinline__ unsigned short f2bf(float f) {
    unsigned u = __float_as_uint(f);
    unsigned r = (u + 0x7fffu + ((u >> 16) & 1u)) >> 16;   // RNE
    return (unsigned short)r;
}
__device__ __forceinline__ float bf2f(unsigned short u) {
    return __uint_as_float(((unsigned)u) << 16);
}
// packed RNE convert: dst = (bf16(hi)<<16) | bf16(lo)
__device__ __forceinline__ unsigned cvtpk(float lo, float hi) {
    unsigned r;
    asm("v_cvt_pk_bf16_f32 %0, %1, %2" : "=v"(r) : "v"(lo), "v"(hi));
    return r;
}

// ---------- fused: producer/consumer wave-specialized dist GEMM ----------
// 128x128 tile, grid (BB, 4), 512 threads. Waves 0-3 PRODUCE (fp32 load -> cvtpk
// -> ds_write staging + row norms); waves 4-7 CONSUME (ds_read frags + MFMA,
// full K=1024 into one acc). Double-buffered LDS, ONE barrier per k-step:
// producers stage step k+1 into buf^1 while consumers compute step k from buf.
// R17 ablations showed the lockstep structure ran VMEM/stage/MFMA as a SUM;
// role-split makes them run concurrently (max instead of sum).
// LDS swizzle: 16B slot s of row r at phys slot s^((r>>1)&3)  (R16, conflicts=0).
__global__ __launch_bounds__(512) void fused_kernel(const float* __restrict__ S,
                                                    const float* __restrict__ T,
                                                    unsigned short* __restrict__ Dd) {
    __shared__ unsigned short lds[2][2][128 * BK];   // [buf][A/B], 32 KB
    __shared__ float nrm[2][128];                    // row norms [side][row]

    const int b    = blockIdx.x;
    const int tile = blockIdx.y;
    const int i0 = (tile & 1) * 128;
    const int j0 = (tile >> 1) * 128;
    const int tid = threadIdx.x, w = tid >> 6, lane = tid & 63;

    const float* Sg = S + ((size_t)b * LL + i0) * DD;
    const float* Tg = T + ((size_t)b * LL + j0) * DD;

    // ---- producer role (waves 0..3) ----
    const int q  = w & 3;                    // producer index / consumer index
    const int sr   = q * 16 + (lane >> 2);   // staging row within 64-row half
    const int slot = lane & 3;               // lds PHYS k-slot this lane fills
    const int kb   = slot ^ ((sr >> 1) & 3); // GLOBAL k-slot (conflict-free swizzle)

    // ---- consumer role (waves 4..7) ----
    const int wr = q >> 1, wc = q & 1;

    float4v acc[4][4];
    const float4v fzero = {0.f, 0.f, 0.f, 0.f};
    #pragma unroll
    for (int mi = 0; mi < 4; ++mi)
        #pragma unroll
        for (int ni = 0; ni < 4; ++ni) acc[mi][ni] = fzero;

    struct Stg { float4 a[2][2]; float4 bb[2][2]; };   // [half n][8-float piece]
    Stg st0, st1;
    float ns[2][2] = {};                      // producer norm accum [side][n]

    auto issue = [&](Stg& s, int kt) {
        const float* pa = Sg + (size_t)sr * DD + kt * BK + kb * 8;
        const float* pb = Tg + (size_t)sr * DD + kt * BK + kb * 8;
        s.a[0][0]  = *(const float4*)(pa);
        s.a[0][1]  = *(const float4*)(pa + 4);
        s.a[1][0]  = *(const float4*)(pa + 64 * DD);
        s.a[1][1]  = *(const float4*)(pa + 64 * DD + 4);
        s.bb[0][0] = *(const float4*)(pb);
        s.bb[0][1] = *(const float4*)(pb + 4);
        s.bb[1][0] = *(const float4*)(pb + 64 * DD);
        s.bb[1][1] = *(const float4*)(pb + 64 * DD + 4);
    };

    auto cvtwrite = [&](const float4& v0, const float4& v1, unsigned short* dst, float& nacc) {
        nacc += v0.x * v0.x + v0.y * v0.y + v0.z * v0.z + v0.w * v0.w
              + v1.x * v1.x + v1.y * v1.y + v1.z * v1.z + v1.w * v1.w;
        uint4 o;
        o.x = cvtpk(v0.x, v0.y);
        o.y = cvtpk(v0.z, v0.w);
        o.z = cvtpk(v1.x, v1.y);
        o.w = cvtpk(v1.z, v1.w);
        *(uint4*)dst = o;
    };

    auto commit = [&](Stg& s, int buf) {
        #pragma unroll
        for (int n = 0; n < 2; ++n) {
            // row = n*64+sr; (row>>1)&3 == (sr>>1)&3 so write swizzle matches kb
            cvtwrite(s.a[n][0],  s.a[n][1],  &lds[buf][0][(n * 64 + sr) * BK + slot * 8], ns[0][n]);
            cvtwrite(s.bb[n][0], s.bb[n][1], &lds[buf][1][(n * 64 + sr) * BK + slot * 8], ns[1][n]);
        }
    };

    auto compute = [&](int buf) {
        const unsigned short* LA = &lds[buf][0][0];
        const unsigned short* LB = &lds[buf][1][0];
        short8v af[4], bf[4];
        #pragma unroll
        for (int mi = 0; mi < 4; ++mi) {
            int row = wr * 64 + mi * 16 + (lane & 15);
            int kbf = (lane >> 4) ^ ((row >> 1) & 3);   // conflict-free read swizzle
            af[mi] = *(const short8v*)(LA + row * BK + kbf * 8);
        }
        #pragma unroll
        for (int ni = 0; ni < 4; ++ni) {
            int row = wc * 64 + ni * 16 + (lane & 15);
            int kbf = (lane >> 4) ^ ((row >> 1) & 3);
            bf[ni] = *(const short8v*)(LB + row * BK + kbf * 8);
        }
        #pragma unroll
        for (int mi = 0; mi < 4; ++mi)
            #pragma unroll
            for (int ni = 0; ni < 4; ++ni)
                acc[mi][ni] = __builtin_amdgcn_mfma_f32_16x16x32_bf16(af[mi], bf[ni],
                                                                      acc[mi][ni], 0, 0, 0);
    };

    // handoff barrier: drain own LDS ops only; global loads stay in flight.
    auto pbar = [&]() {
        asm volatile("s_waitcnt lgkmcnt(0)" ::: "memory");
        __builtin_amdgcn_s_barrier();
        __builtin_amdgcn_sched_barrier(0);
    };

    // prologue: producers stage step 0 into buf0, issue step 1
    if (w < 4) {
        issue(st0, 0);
        issue(st1, 1);
        commit(st0, 0);
    }
    pbar();

    for (int kt = 0; kt < 32; kt += 2) {
        // half A: consumers eat buf0 (step kt); producers fill buf1 (step kt+1)
        if (w < 4) {
            if (kt + 2 < 32) issue(st0, kt + 2);
            commit(st1, 1);
        } else {
            compute(0);
        }
        pbar();
        // half B: consumers eat buf1 (step kt+1); producers fill buf0 (step kt+2)
        if (w < 4) {
            if (kt + 3 < 32) issue(st1, kt + 3);
            if (kt + 2 < 32) commit(st0, 0);
        } else {
            compute(1);
        }
        pbar();
    }

    // producers: finalize row norms (reduce across the 4 slot-lanes per row)
    if (w < 4) {
        #pragma unroll
        for (int side = 0; side < 2; ++side)
            #pragma unroll
            for (int n = 0; n < 2; ++n) {
                float s = ns[side][n];
                s += __shfl_xor(s, 1, 64);
                s += __shfl_xor(s, 2, 64);
                if (slot == 0) nrm[side][n * 64 + sr] = s;
            }
    }
    __syncthreads();

    // consumers: epilogue sq = ||s||^2 + ||t||^2 - 2*dot -> sqrt -> bf16*LOG2E
    if (w >= 4) {
        const int r0 = (lane >> 4) * 4;
        const int cf = lane & 15;
        unsigned short* Db = Dd + (size_t)b * NDPAD * 256;
        #pragma unroll
        for (int mi = 0; mi < 4; ++mi) {
            #pragma unroll
            for (int ni = 0; ni < 4; ++ni) {
                int lj = wc * 64 + ni * 16 + cf;
                float tj = nrm[1][lj];
                int j = j0 + lj;
                #pragma unroll
                for (int rg = 0; rg < 4; ++rg) {
                    int li = wr * 64 + mi * 16 + r0 + rg;
                    float sq = nrm[0][li] + tj - 2.0f * acc[mi][ni][rg];
                    float dv = sqrtf(fmaxf(sq, 1e-12f));
                    int i = i0 + li;
                    Db[(size_t)(i + j) * 256 + j] = f2bf(dv * LOG2E);
                }
            }
        }
    }
}

// ---------- soft-DTW DP: 4 waves per batch, chunk-skewed wavefront ----------
// lane i <- lane i-1 via DPP wave_shr:1; lane 0 <- fill
__device__ __forceinline__ float wshr1(float src, float fill) {
    return __int_as_float(__builtin_amdgcn_update_dpp(
        __float_as_int(fill), __float_as_int(src), 0x138, 0xF, 0xF, false));
}

__global__ __launch_bounds__(256) void sdtw_kernel(const unsigned short* __restrict__ Dg,
                                                   float* __restrict__ res) {
    __shared__ unsigned short sd[8][16 * 256];
    __shared__ float bbuf[3][2][16];
    const int b = blockIdx.x;
    const int tid = threadIdx.x;
    const int w = tid >> 6;
    const int lane = tid & 63;
    const float INF = INFINITY;
    const unsigned short* Db = Dg + (size_t)b * NDPAD * 256;

    auto prefetch = [&](int c) {
        #pragma unroll
        for (int q = 0; q < 8; ++q) {
            __builtin_amdgcn_global_load_lds(
                (const __attribute__((address_space(1))) void*)(Db + (size_t)c * 4096 + q * 512 + lane * 8),
                (__attribute__((address_space(3))) void*)(&sd[c & 7][q * 512]),
                16, 0, 0);
        }
    };

    const int col0 = 64 * w + lane;
    float rm1 = INF, rm2 = INF;
    float p2carry = (tid == 0) ? 0.0f : INF;
    float bcarry = INF;

    if (w == 0) {
        prefetch(0);
        prefetch(1);
        asm volatile("s_waitcnt vmcnt(8)" ::: "memory");
    }
    asm volatile("s_waitcnt lgkmcnt(0)" ::: "memory");
    __builtin_amdgcn_s_barrier();

    for (int r = 0; r < 35; ++r) {
        if (w == 0 && r + 2 < 32) prefetch(r + 2);
        const int c = r - w;
        if (0 <= c && c < 32) {
            const unsigned short* Lp = &sd[c & 7][0];
            float dv[16];
            #pragma unroll
            for (int q = 0; q < 16; ++q)
                dv[q] = bf2f(Lp[q * 256 + col0]);

            float bv[16];
            if (w == 0) {
                #pragma unroll
                for (int q = 0; q < 16; ++q) bv[q] = INF;
            } else {
                const float4* bp4 = (const float4*)&bbuf[w - 1][c & 1][0];
                float4 b0 = bp4[0], b1 = bp4[1], b2 = bp4[2], b3 = bp4[3];
                bv[0] = bcarry;
                bv[1] = b0.x;  bv[2] = b0.y;  bv[3] = b0.z;  bv[4] = b0.w;
                bv[5] = b1.x;  bv[6] = b1.y;  bv[7] = b1.z;  bv[8] = b1.w;
                bv[9] = b2.x;  bv[10] = b2.y; bv[11] = b2.z; bv[12] = b2.w;
                bv[13] = b3.x; bv[14] = b3.y; bv[15] = b3.z;
                bcarry = b3.w;
            }
            asm volatile("s_waitcnt lgkmcnt(0)" ::: "memory");
            __builtin_amdgcn_sched_barrier(0);

            const int ibase = 16 * c - col0;
            float bb[16];
            #pragma unroll
            for (int q = 0; q < 16; ++q) {
                float p1 = wshr1(rm1, bv[q]);
                float p2 = p2carry;
                p2carry = p1;
                float m   = fminf(p2, fminf(rm1, p1));
                float mid = __builtin_amdgcn_fmed3f(p2, rm1, p1);
                float M   = fmaxf(p2, fmaxf(rm1, p1));
                float s   = (__builtin_amdgcn_exp2f(m - mid) +
                             __builtin_amdgcn_exp2f(m - M)) + 1.0f;
                float rcv = dv[q] + m - __builtin_amdgcn_logf(s);
                bool valid = (unsigned)(ibase + q) < 256u;
                rcv = valid ? rcv : INF;
                rm2 = rm1;
                rm1 = rcv;
                bb[q] = rcv;
            }
            if (w < 3 && lane == 63) {
                float4* op = (float4*)&bbuf[w][c & 1][0];
                op[0] = make_float4(bb[0], bb[1], bb[2], bb[3]);
                op[1] = make_float4(bb[4], bb[5], bb[6], bb[7]);
                op[2] = make_float4(bb[8], bb[9], bb[10], bb[11]);
                op[3] = make_float4(bb[12], bb[13], bb[14], bb[15]);
            }
        }
        if (w == 0) {
            if (r < 30) asm volatile("s_waitcnt vmcnt(8)" ::: "memory");
            else        asm volatile("s_waitcnt vmcnt(0)" ::: "memory");
        }
        asm volatile("s_waitcnt lgkmcnt(0)" ::: "memory");
        __builtin_amdgcn_s_barrier();
    }
    if (tid == 255) res[b] = rm2 * LN2;
}

// ---------- final mean over batches ----------
__global__ void reduce_kernel(const float* __restrict__ res, float* __restrict__ out) {
    int t = threadIdx.x;
    float v = res[t];
    #pragma unroll
    for (int off = 32; off; off >>= 1) v += __shfl_down(v, off, 64);
    if (t == 0) out[0] = v * (1.0f / BB);
}

extern "C" void kernel_launch(void* const* d_in, const int* in_sizes, int n_in,
                              void* d_out, int out_size, void* d_ws, size_t ws_size,
                              hipStream_t stream) {
    const float* S = (const float*)d_in[0];
    const float* T = (const float*)d_in[1];

    const size_t nDiag = (size_t)BB * NDPAD * 256;   // 8,388,608 ushorts (16.8 MB)
    unsigned short* diag = (unsigned short*)d_ws;
    float* rsv = (float*)(diag + nDiag);

    fused_kernel<<<dim3(BB, 4), 512, 0, stream>>>(S, T, diag);
    sdtw_kernel<<<BB, 256, 0, stream>>>(diag, rsv);
    reduce_kernel<<<1, 64, 0, stream>>>(rsv, (float*)d_out);
}